// Round 6
// baseline (76.195 us; speedup 1.0000x reference)
//
#include <hip/hip_runtime.h>
#include <hip/hip_cooperative_groups.h>

namespace cg = cooperative_groups;

// Cost volume loss: pred/target (8,3,512,512) f32.
// Per pixel: min over 5x5 offsets (zero-padded target) of mean_C |pred - patch|,
// then global mean. Output: single f32 scalar.
//
// Single cooperative kernel. Thread = 4 cols x 4 rows. Block = 512 cols x 8 rows
// (128 col-threads x 2 row-groups). Grid = 8 n * 64 hgrps = 512 blocks = 2/CU.
// Border pixels seed `best` with the zero-pad candidate (sum|pred|), so the
// inner loop has no h-edge path; invalid-dj windows are suppressed with +INF.

#define H_DIM 512
#define W_DIM 512
#define N_DIM 8
#define C_DIM 3
#define HW (H_DIM * W_DIM)
#define CHW (C_DIM * HW)
#define NPIX (N_DIM * HW)
#define NBLOCKS 512
#define BIGF 3.0e38f

typedef float f4 __attribute__((ext_vector_type(4)));

__global__ __launch_bounds__(256, 4) void cvl_fused(const float* __restrict__ pred,
                                                    const float* __restrict__ targ,
                                                    float* __restrict__ partial,
                                                    float* __restrict__ out) {
    const int tid = threadIdx.x;
    const int col = tid & 127;        // 0..127
    const int rg  = tid >> 7;         // 0..1 (wave-uniform)
    const int bid = blockIdx.x;       // 0..511
    const int n   = bid >> 6;         // 0..7
    const int hg  = bid & 63;         // 0..63
    const int h0  = hg * 8 + rg * 4;  // first of this thread's 4 rows
    const int w0  = col * 4;          // first of this thread's 4 cols

    const size_t nbase = (size_t)n * CHW;

    // ---- pred: 4 rows x 3 channels x 4 pixels, nontemporal (streamed once) ----
    float pf[4][3][4];
#pragma unroll
    for (int r = 0; r < 4; ++r) {
#pragma unroll
        for (int c = 0; c < 3; ++c) {
            const f4 v = __builtin_nontemporal_load(
                (const f4*)(pred + nbase + (size_t)c * HW +
                            (size_t)(h0 + r) * W_DIM + w0));
            pf[r][c][0] = v.x; pf[r][c][1] = v.y; pf[r][c][2] = v.z; pf[r][c][3] = v.w;
        }
    }

    const bool wlo = (col == 0);          // w0 == 0
    const bool whi = (col == 127);        // w0 == 508

    // ---- seed best: border pixels get the zero-pad candidate sum|pred| ----
    float best[4][4];
#pragma unroll
    for (int r = 0; r < 4; ++r) {
        const int hp = h0 + r;
        const bool hcand = (hp < 2) || (hp >= H_DIM - 2);
#pragma unroll
        for (int px = 0; px < 4; ++px) {
            const bool wcand = (px < 2) ? wlo : whi;
            const float soob = fabsf(pf[r][0][px]) + fabsf(pf[r][1][px]) + fabsf(pf[r][2][px]);
            best[r][px] = (hcand || wcand) ? soob : BIGF;
        }
    }

    const int offm = wlo ? 0 : (w0 - 4);
    const int offp = whi ? (W_DIM - 4) : (w0 + 4);

    // ---- 8 target rows per thread, direct loads (L1/L2/L3 serve reuse) ----
#pragma unroll
    for (int j = 0; j < 8; ++j) {
        const int hh = h0 - 2 + j;
        if (hh >= 0 && hh < H_DIM) {       // wave-uniform -> scalar branch
            float tw[3][12];
#pragma unroll
            for (int c = 0; c < 3; ++c) {
                const float* rowp = targ + nbase + (size_t)c * HW + (size_t)hh * W_DIM;
                const f4 a = *(const f4*)(rowp + offm);
                const f4 b = *(const f4*)(rowp + w0);
                const f4 d = *(const f4*)(rowp + offp);
                tw[c][0] = a.x;  tw[c][1] = a.y;  tw[c][2]  = a.z;  tw[c][3]  = a.w;
                tw[c][4] = b.x;  tw[c][5] = b.y;  tw[c][6]  = b.z;  tw[c][7]  = b.w;
                tw[c][8] = d.x;  tw[c][9] = d.y;  tw[c][10] = d.z;  tw[c][11] = d.w;
            }
#pragma unroll
            for (int r = 0; r < 4; ++r) {
                const int di = j - 2 - r;            // compile-time after unroll
                if (di >= -2 && di <= 2) {
#pragma unroll
                    for (int px = 0; px < 4; ++px) {
#pragma unroll
                        for (int dj = -2; dj <= 2; ++dj) {
                            const int ix = 4 + px + dj;  // 2..9
                            float s = fabsf(pf[r][0][px] - tw[0][ix])
                                    + fabsf(pf[r][1][px] - tw[1][ix])
                                    + fabsf(pf[r][2][px] - tw[2][ix]);
                            // clamped-load windows are invalid at image edges:
                            if (px + dj < 0)      s = wlo ? BIGF : s;
                            else if (px + dj > 3) s = whi ? BIGF : s;
                            best[r][px] = fminf(best[r][px], s);
                        }
                    }
                }
            }
        }
        // hh out of image: zero-pad candidate already seeded into best.
    }

    // ---- block reduce: 16 px -> thread, wave shuffle, LDS, one store/block ----
    float v = 0.0f;
#pragma unroll
    for (int r = 0; r < 4; ++r)
#pragma unroll
        for (int px = 0; px < 4; ++px)
            v += best[r][px];

#pragma unroll
    for (int o = 32; o > 0; o >>= 1) v += __shfl_down(v, o, 64);

    __shared__ float ws[4];
    const int lane = tid & 63;
    const int wv   = tid >> 6;
    if (lane == 0) ws[wv] = v;
    __syncthreads();
    if (tid == 0) partial[bid] = ws[0] + ws[1] + ws[2] + ws[3];

    // ---- grid-wide sync, then block 0 reduces the 512 partials ----
    cg::this_grid().sync();

    if (bid == 0) {
        double dv = (double)partial[tid] + (double)partial[tid + 256];
#pragma unroll
        for (int o = 32; o > 0; o >>= 1) dv += __shfl_down(dv, o, 64);

        __shared__ double wd[4];
        if (lane == 0) wd[wv] = dv;
        __syncthreads();
        if (tid == 0) {
            const double s = wd[0] + wd[1] + wd[2] + wd[3];
            out[0] = (float)(s / (3.0 * (double)NPIX));
        }
    }
}

extern "C" void kernel_launch(void* const* d_in, const int* in_sizes, int n_in,
                              void* d_out, int out_size, void* d_ws, size_t ws_size,
                              hipStream_t stream) {
    const float* pred = (const float*)d_in[0];
    const float* targ = (const float*)d_in[1];
    float* out = (float*)d_out;
    float* partial = (float*)d_ws;

    void* args[] = {(void*)&pred, (void*)&targ, (void*)&partial, (void*)&out};
    (void)hipLaunchCooperativeKernel((void*)cvl_fused, dim3(NBLOCKS), dim3(256),
                                     args, 0, stream);
}

// Round 7
// 23.266 us; speedup vs baseline: 3.2749x; 3.2749x over previous
//
#include <hip/hip_runtime.h>

// Cost volume loss: pred/target (8,3,512,512) f32.
// Per pixel: min over 5x5 offsets (zero-padded target) of mean_C |pred - patch|,
// then global mean. Output: single f32 scalar.
//
// Two kernels (grid.sync proved ~40us; a 1-block final kernel is cheaper).
// Thread = 4 cols x 4 rows; block = 512 cols x 8 rows; grid = 512 blocks.
// launch_bounds(256,2): let the compiler use up to ~256 VGPR for ILP — the
// 512-block grid caps occupancy at 8 waves/CU anyway, so spend registers on
// a depth-1 software pipeline (load row j+1 windows while computing row j).

#define H_DIM 512
#define W_DIM 512
#define N_DIM 8
#define C_DIM 3
#define HW (H_DIM * W_DIM)
#define CHW (C_DIM * HW)
#define NPIX (N_DIM * HW)
#define NBLOCKS 512
#define BIGF 3.0e38f

typedef float f4 __attribute__((ext_vector_type(4)));

__global__ __launch_bounds__(256, 2) void cvl_main(const float* __restrict__ pred,
                                                   const float* __restrict__ targ,
                                                   float* __restrict__ partial) {
    const int tid = threadIdx.x;
    const int col = tid & 127;        // 0..127
    const int rg  = tid >> 7;         // 0..1 (wave-uniform)
    const int bid = blockIdx.x;       // 0..511
    const int n   = bid >> 6;         // 0..7
    const int hg  = bid & 63;         // 0..63
    const int h0  = hg * 8 + rg * 4;  // first of this thread's 4 rows
    const int w0  = col * 4;          // first of this thread's 4 cols

    const size_t nbase = (size_t)n * CHW;

    // ---- pred: 4 rows x 3 channels x 4 px, nontemporal (streamed once) ----
    f4 pv[4][3];
#pragma unroll
    for (int r = 0; r < 4; ++r)
#pragma unroll
        for (int c = 0; c < 3; ++c)
            pv[r][c] = __builtin_nontemporal_load(
                (const f4*)(pred + nbase + (size_t)c * HW +
                            (size_t)(h0 + r) * W_DIM + w0));

    const bool wlo = (col == 0);          // w0 == 0
    const bool whi = (col == 127);        // w0 == 508
    const int offm = wlo ? 0 : (w0 - 4);
    const int offp = whi ? (W_DIM - 4) : (w0 + 4);
    const float* trow = targ + nbase;

    // ---- seed best: border pixels get the zero-pad candidate sum|pred| ----
    float best[4][4];
#pragma unroll
    for (int r = 0; r < 4; ++r) {
        const int hp = h0 + r;
        const bool hcand = (hp < 2) || (hp >= H_DIM - 2);
#pragma unroll
        for (int px = 0; px < 4; ++px) {
            const bool wcand = (px < 2) ? wlo : whi;
            const float soob = fabsf(pv[r][0][px]) + fabsf(pv[r][1][px]) + fabsf(pv[r][2][px]);
            best[r][px] = (hcand || wcand) ? soob : BIGF;
        }
    }

    // ---- depth-1 pipelined row loop over the 8 target rows ----
    float tw[2][3][12];

    auto loadrow = [&](int j) __attribute__((always_inline)) {
        const int hh = h0 - 2 + j;
        if (hh >= 0 && hh < H_DIM) {       // wave-uniform
            float(*dst)[12] = tw[j & 1];
#pragma unroll
            for (int c = 0; c < 3; ++c) {
                const float* rowp = trow + (size_t)c * HW + (size_t)hh * W_DIM;
                const f4 a = *(const f4*)(rowp + offm);
                const f4 b = *(const f4*)(rowp + w0);
                const f4 d = *(const f4*)(rowp + offp);
                dst[c][0] = a[0];  dst[c][1] = a[1];  dst[c][2]  = a[2];  dst[c][3]  = a[3];
                dst[c][4] = b[0];  dst[c][5] = b[1];  dst[c][6]  = b[2];  dst[c][7]  = b[3];
                dst[c][8] = d[0];  dst[c][9] = d[1];  dst[c][10] = d[2];  dst[c][11] = d[3];
            }
        }
    };

    auto comprow = [&](int j) __attribute__((always_inline)) {
        const int hh = h0 - 2 + j;
        if (hh >= 0 && hh < H_DIM) {       // wave-uniform
            const float(*src)[12] = tw[j & 1];
#pragma unroll
            for (int r = 0; r < 4; ++r) {
                const int di = j - 2 - r;          // constant after unroll/inline
                if (di >= -2 && di <= 2) {
#pragma unroll
                    for (int px = 0; px < 4; ++px) {
#pragma unroll
                        for (int dj = -2; dj <= 2; ++dj) {
                            const int ix = 4 + px + dj;  // 2..9
                            float s = fabsf(pv[r][0][px] - src[0][ix])
                                    + fabsf(pv[r][1][px] - src[1][ix])
                                    + fabsf(pv[r][2][px] - src[2][ix]);
                            // clamped-window candidates are invalid at image edges:
                            if (px + dj < 0)      s = wlo ? BIGF : s;
                            else if (px + dj > 3) s = whi ? BIGF : s;
                            best[r][px] = fminf(best[r][px], s);
                        }
                    }
                }
            }
        }
        // hh out of image: zero-pad candidate already seeded into best.
    };

    loadrow(0);
#pragma unroll
    for (int j = 0; j < 8; ++j) {
        if (j + 1 < 8) loadrow(j + 1);   // issue next row's loads first...
        comprow(j);                      // ...then compute current row
    }

    // ---- block reduce: 16 px -> thread, wave shuffle, LDS, one store ----
    float v = 0.0f;
#pragma unroll
    for (int r = 0; r < 4; ++r)
#pragma unroll
        for (int px = 0; px < 4; ++px)
            v += best[r][px];

#pragma unroll
    for (int o = 32; o > 0; o >>= 1) v += __shfl_down(v, o, 64);

    __shared__ float ws[4];
    const int lane = tid & 63;
    const int wv   = tid >> 6;
    if (lane == 0) ws[wv] = v;
    __syncthreads();
    if (tid == 0) partial[bid] = ws[0] + ws[1] + ws[2] + ws[3];
}

__global__ __launch_bounds__(256) void cvl_final(const float* __restrict__ partial,
                                                 float* __restrict__ out) {
    const int tid = threadIdx.x;
    double v = (double)partial[tid] + (double)partial[tid + 256];
#pragma unroll
    for (int o = 32; o > 0; o >>= 1) v += __shfl_down(v, o, 64);

    __shared__ double ws[4];
    const int lane = tid & 63;
    const int wid  = tid >> 6;
    if (lane == 0) ws[wid] = v;
    __syncthreads();
    if (tid == 0) {
        const double s = ws[0] + ws[1] + ws[2] + ws[3];
        out[0] = (float)(s / (3.0 * (double)NPIX));
    }
}

extern "C" void kernel_launch(void* const* d_in, const int* in_sizes, int n_in,
                              void* d_out, int out_size, void* d_ws, size_t ws_size,
                              hipStream_t stream) {
    const float* pred = (const float*)d_in[0];
    const float* targ = (const float*)d_in[1];
    float* out = (float*)d_out;
    float* partial = (float*)d_ws;

    cvl_main<<<NBLOCKS, 256, 0, stream>>>(pred, targ, partial);
    cvl_final<<<1, 256, 0, stream>>>(partial, out);
}